// Round 11
// baseline (97.788 us; speedup 1.0000x reference)
//
#include <hip/hip_runtime.h>
#include <hip/hip_fp16.h>

#define IMG   256
#define SROWS 32    // output rows per block
#define RAWR  60    // SROWS + 2*PAD raw rows staged
#define KS    29
#define PAD   14
#define LDSS  292   // tmp row stride (f32); word-stride 292 == 4 mod 32 -> b128 lane=row reads full-BW
#define MOFF  16    // tmp main-data offset (layout offset = padded position + 2)

// exp(-d^2/(2*49)) for d=0..14; normalization folds at compile time.
static constexpr float GK[15] = {
    1.0f,        0.98984780f, 0.96000544f, 0.91225408f, 0.84936581f,
    0.77483743f, 0.69256933f, 0.60653066f, 0.52045012f, 0.43756474f,
    0.36044779f, 0.29092381f, 0.23006630f, 0.17826398f, 0.13533528f
};
static constexpr float GSUM =
    GK[0] + 2.0f * (GK[1] + GK[2] + GK[3] + GK[4] + GK[5] + GK[6] + GK[7] +
                    GK[8] + GK[9] + GK[10] + GK[11] + GK[12] + GK[13] + GK[14]);
static constexpr float WT[29] = {
    GK[14]/GSUM, GK[13]/GSUM, GK[12]/GSUM, GK[11]/GSUM, GK[10]/GSUM, GK[9]/GSUM, GK[8]/GSUM,
    GK[7]/GSUM,  GK[6]/GSUM,  GK[5]/GSUM,  GK[4]/GSUM,  GK[3]/GSUM,  GK[2]/GSUM, GK[1]/GSUM,
    GK[0]/GSUM,
    GK[1]/GSUM,  GK[2]/GSUM,  GK[3]/GSUM,  GK[4]/GSUM,  GK[5]/GSUM,  GK[6]/GSUM, GK[7]/GSUM,
    GK[8]/GSUM,  GK[9]/GSUM,  GK[10]/GSUM, GK[11]/GSUM, GK[12]/GSUM, GK[13]/GSUM, GK[14]/GSUM
};

__device__ __forceinline__ int refl(int p) {
    int a = p < 0 ? -p : p;        // reflect at 0
    int b = 2 * (IMG - 1) - a;     // reflect at 255
    return a < b ? a : b;
}

__global__ __launch_bounds__(512, 4)   // 128-VGPR cap; 2 blocks/CU (LDS 68.1 KB)
void gauss_v11(const float* __restrict__ x, float* __restrict__ out) {
    __shared__ __half raw[RAWR * 256];   // 30,720 B  (f16 staged input, 32-row strip + 28 halo)
    __shared__ float  tmp[SROWS * LDSS]; // 37,376 B  (vertical-conv result + horizontal halo)

    const int t   = threadIdx.x;
    const int img = blockIdx.y;
    const int y0  = blockIdx.x * SROWS;

    const float* __restrict__ src = x   + (size_t)img * (IMG * IMG);
    float*       __restrict__ dst = out + (size_t)img * (IMG * IMG);

    // ---- Phase 0: stage raw rows [y0-14, y0+45] (reflected) into LDS as f16.
    //      3840 float4-items; pure independent load->convert->store burst.
    #pragma unroll
    for (int k = 0; k < 8; ++k) {
        const int i = t + k * 512;
        if (i < RAWR * 64) {
            const int r  = i >> 6;
            const int c4 = (i & 63) << 2;
            const int gr = refl(y0 - PAD + r);
            const float4 v = *(const float4*)(src + (size_t)gr * IMG + c4);
            __half2 a = __float22half2_rn(make_float2(v.x, v.y));
            __half2 b = __float22half2_rn(make_float2(v.z, v.w));
            uint2 pk;
            pk.x = *(unsigned int*)&a;
            pk.y = *(unsigned int*)&b;
            *(uint2*)&raw[r * 256 + c4] = pk;   // 8B store, lanes contiguous
        }
    }
    __syncthreads();

    // ---- Phase 1: vertical conv from LDS raw. thread = (colpair cp 0..127, rowgroup rg 0..3).
    //      8 output rows x 2 cols per thread; 36-row window; reads are row-uniform
    //      64x4B contiguous -> conflict-free; writes b64 contiguous -> conflict-free.
    {
        const int cp = t & 127;
        const int rg = t >> 7;            // wave-uniform
        const int r0 = rg * 8;

        float2 acc[8];
        #pragma unroll
        for (int j = 0; j < 8; ++j) acc[j] = make_float2(0.f, 0.f);

        #pragma unroll
        for (int s = 0; s < 36; ++s) {
            const __half2 h = *(__half2*)&raw[(r0 + s) * 256 + 2 * cp];
            const float2 v = __half22float2(h);
            #pragma unroll
            for (int j = 0; j < 8; ++j) {
                const int k = s - j;
                if (k >= 0 && k < KS) {
                    acc[j].x += WT[k] * v.x;
                    acc[j].y += WT[k] * v.y;
                }
            }
        }

        #pragma unroll
        for (int j = 0; j < 8; ++j)
            *(float2*)&tmp[(r0 + j) * LDSS + MOFF + 2 * cp] = acc[j];

        // mirrored horizontal halo (reflect-101):
        //   left : col c (1..14)    -> offset MOFF - c            (2..15)
        //   right: col c (241..254) -> offset MOFF + 510 - c      (272..285)
        if (cp <= 7) {
            #pragma unroll
            for (int q = 0; q < 2; ++q) {
                const int c = 2 * cp + q;
                if (c >= 1 && c <= PAD) {
                    #pragma unroll
                    for (int j = 0; j < 8; ++j)
                        tmp[(r0 + j) * LDSS + (MOFF - c)] = q == 0 ? acc[j].x : acc[j].y;
                }
            }
        } else if (cp >= 120) {
            #pragma unroll
            for (int q = 0; q < 2; ++q) {
                const int c = 2 * cp + q;
                if (c >= IMG - 1 - PAD && c <= IMG - 2) {
                    #pragma unroll
                    for (int j = 0; j < 8; ++j)
                        tmp[(r0 + j) * LDSS + (MOFF + 2 * (IMG - 1) - c)] = q == 0 ? acc[j].x : acc[j].y;
                }
            }
        }
    }
    __syncthreads();

    // ---- Phase 2: horizontal conv. thread = (row 0..31, colgroup 0..15), 16 cols/thread.
    //      12 aligned b128 reads at word-stride 292 (==4 mod 32): 8 lanes/round cover
    //      all 32 banks -> full LDS BW. Element e at layout off c0b+e is padded pos
    //      c0b+e-2; tap for output col c0b+c is k = e-2-c.
    {
        const int row = t & 31;
        const int cg  = t >> 5;          // 0..15
        const int c0b = cg * 16;

        float acc[16];
        #pragma unroll
        for (int c = 0; c < 16; ++c) acc[c] = 0.f;

        const float4* w = (const float4*)&tmp[row * LDSS + c0b];   // 16B-aligned
        #pragma unroll
        for (int m = 0; m < 12; ++m) {
            const float4 v4 = w[m];
            #pragma unroll
            for (int q = 0; q < 4; ++q) {
                const int e = 4 * m + q;
                const float val = q == 0 ? v4.x : q == 1 ? v4.y : q == 2 ? v4.z : v4.w;
                #pragma unroll
                for (int c = 0; c < 16; ++c) {
                    const int k = e - 2 - c;
                    if (k >= 0 && k < KS) acc[c] += WT[k] * val;
                }
            }
        }

        float4* orow = (float4*)&dst[(size_t)(y0 + row) * IMG + c0b];
        #pragma unroll
        for (int m = 0; m < 4; ++m)
            orow[m] = make_float4(acc[4*m+0], acc[4*m+1], acc[4*m+2], acc[4*m+3]);
    }
}

extern "C" void kernel_launch(void* const* d_in, const int* in_sizes, int n_in,
                              void* d_out, int out_size, void* d_ws, size_t ws_size,
                              hipStream_t stream) {
    const float* x = (const float*)d_in[0];
    float* out = (float*)d_out;
    const int images = in_sizes[0] / (IMG * IMG);   // 8*64 = 512
    dim3 grid(IMG / SROWS, images);                 // (8, 512)
    gauss_v11<<<grid, dim3(512), 0, stream>>>(x, out);
}